// Round 7
// baseline (339.870 us; speedup 1.0000x reference)
//
#include <hip/hip_runtime.h>

typedef unsigned short bhalf;          // bf16 bits
typedef __attribute__((ext_vector_type(4))) float    f32x4;
typedef __attribute__((ext_vector_type(8))) short    s16x8;
typedef __attribute__((ext_vector_type(4))) float    floatx4;
typedef __attribute__((ext_vector_type(4))) unsigned short u16x4;

#define B_  2
#define S_  2048
#define HID_ 2048
#define NH_ 16
#define HD_ 128
#define M_  (B_*S_)          // 4096
#define MASKV (-10000.0f)

__device__ __forceinline__ bhalf f32_to_bf16(float f) {
    union { float f; unsigned int u; } v; v.f = f;
    unsigned int r = v.u + 0x7FFFu + ((v.u >> 16) & 1u);   // RNE
    return (bhalf)(r >> 16);
}
__device__ __forceinline__ bhalf f32_to_bf16_trunc(float f) {
    union { float f; unsigned int u; } v; v.f = f;
    return (bhalf)(v.u >> 16);
}
__device__ __forceinline__ float bf16_to_f32(bhalf h) {
    union { unsigned int u; float f; } v; v.u = ((unsigned int)h) << 16;
    return v.f;
}

// async global->LDS, 16B per lane; LDS dest = wave-uniform base + lane*16
__device__ __forceinline__ void gl_lds16(const void* g, void* l) {
    __builtin_amdgcn_global_load_lds(
        (const __attribute__((address_space(1))) void*)g,
        (__attribute__((address_space(3))) void*)l, 16, 0, 0);
}

// raw barrier with memory clobber: stops compiler memory reordering across
// phases but (unlike sched_barrier(0)) leaves register scheduling free.
#define BARRIER() asm volatile("s_barrier" ::: "memory")

// ------- fused cast fp32 -> bf16 (hs+Wq+Wk+Wv) + RoPE table precompute -----
__global__ __launch_bounds__(256) void cast_all(const float* __restrict__ hs,
                                                const float* __restrict__ Wq,
                                                const float* __restrict__ Wk,
                                                const float* __restrict__ Wv,
                                                bhalf* __restrict__ dst,
                                                float2* __restrict__ tab) {
    if (blockIdx.x >= 20480) {                 // RoPE table: 65536 = 2048 x 32
        int idx = (blockIdx.x - 20480) * 256 + threadIdx.x;
        int i = idx & 31, s = idx >> 5;
        float inv = expf(-(float)i * 0.2878231366242557f);   // ln(10000)/32
        float ang = (float)s * inv;
        tab[idx] = make_float2(sinf(ang), cosf(ang));
        return;
    }
    int idx = blockIdx.x * 256 + threadIdx.x;           // 0 .. 5,242,879
    const float* src;
    if (idx < 2097152)      src = hs + (size_t)idx * 4;
    else if (idx < 3145728) src = Wq + (size_t)(idx - 2097152) * 4;
    else if (idx < 4194304) src = Wk + (size_t)(idx - 3145728) * 4;
    else                    src = Wv + (size_t)(idx - 4194304) * 4;
    floatx4 f = *(const floatx4*)src;
    u16x4 o;
    o.x = f32_to_bf16(f.x); o.y = f32_to_bf16(f.y);
    o.z = f32_to_bf16(f.z); o.w = f32_to_bf16(f.w);
    *(u16x4*)(dst + (size_t)idx * 4) = o;
}

// ---------------- fused QKV GEMM: 256x128 tile, 4-phase counted-vmcnt ------
// R5 structure (verified: 116.4 us, MfmaUtil 38).  R6: RoPE fused into the
// z<2 epilogue.  In this layout d = (col&127) = wx*64 + nt*16 + l, so d<64
// (the roped dims) lives entirely in wx==0 waves, and the rotate pair
// (2i,2i+1) is lanes (l, l^1): one __shfl_xor per value + a tab[s*32+i]
// L2 load.  This removes the rope_apply kernel (8us run + Q/K RMW traffic +
// 2 launch boundaries) and applies rope to f32 pre-rounding (closer to ref).
__global__ __launch_bounds__(512, 2) void qkv_gemm(const bhalf* __restrict__ A,
                                                   const bhalf* __restrict__ Wb,
                                                   const float* __restrict__ bq,
                                                   const float* __restrict__ bk,
                                                   const float* __restrict__ bv,
                                                   bhalf* __restrict__ Out,
                                                   bhalf* __restrict__ VTo,
                                                   const float2* __restrict__ tab) {
    __shared__ __align__(16) bhalf As[2][16384];   // 2 x 256 rows x 64 k
    __shared__ __align__(16) bhalf Bs[2][8192];    // 2 x 128 rows x 64 k
    const int tid  = threadIdx.x;
    const int lane = tid & 63, w = tid >> 6;
    const int quad = lane >> 4, l = lane & 15;
    const int wy = w >> 1, wx = w & 1;            // wave tile: 64 x 64
    const int m0 = blockIdx.x * 256, n0 = blockIdx.y * 128;
    const int z  = blockIdx.z;
    const bhalf* W    = Wb + (size_t)z * HID_ * HID_;
    const float* bias = (z == 0) ? bq : (z == 1) ? bk : bv;
    bhalf* out        = Out + (size_t)z * M_ * HID_;

    bhalf* AsF = &As[0][0];
    bhalf* BsF = &Bs[0][0];

    const int row_s = tid >> 3;                   // 0..63 within a stage unit
    const int kg_s  = (tid & 7) ^ (row_s & 7);    // inverse-swizzled source col-group
    const int w512  = w * 512;                    // wave-uniform LDS slot base

    // running global stage pointers (position = current K-tile t)
    const bhalf* gA0 = A + (size_t)(m0 +   0 + row_s) * HID_ + kg_s * 8;
    const bhalf* gA1 = A + (size_t)(m0 +  64 + row_s) * HID_ + kg_s * 8;
    const bhalf* gA2 = A + (size_t)(m0 + 128 + row_s) * HID_ + kg_s * 8;
    const bhalf* gA3 = A + (size_t)(m0 + 192 + row_s) * HID_ + kg_s * 8;
    const bhalf* gB0 = W + (size_t)(n0 +   0 + row_s) * HID_ + kg_s * 8;
    const bhalf* gB1 = W + (size_t)(n0 +  64 + row_s) * HID_ + kg_s * 8;

    // loop-invariant LDS fragment addressing: row&7 == l&7 for every frag row
    const int aIdx = (wy * 64 + l) * 64;           // element idx of A row base
    const int bIdx = (wx * 64 + l) * 64;           // element idx of B row base
    const int swz0 = ((0 + quad) ^ (l & 7)) * 8;   // ks=0 swizzled chunk
    const int swz1 = ((4 + quad) ^ (l & 7)) * 8;   // ks=1 swizzled chunk

    f32x4 acc[4][4] = {};

#define ADV() do { gA0 += 64; gA1 += 64; gA2 += 64; gA3 += 64;               \
                   gB0 += 64; gB1 += 64; } while (0)

#define KTILE(BUF, ST1, ST2, VM) do {                                        \
    const int CA = (BUF) * 16384, NA = ((BUF) ^ 1) * 16384;                  \
    const int CBB = (BUF) * 8192;                                            \
    s16x8 a_[4][2], b01_[2][2], b23_[2][2];                                  \
    /* ---- P1: read a(8) + b01(4) ; stage A2,A3(t+1) -> NB ---- */          \
    _Pragma("unroll") for (int mt = 0; mt < 4; ++mt) {                       \
        a_[mt][0] = *(const s16x8*)(AsF + CA + aIdx + mt * 1024 + swz0);     \
        a_[mt][1] = *(const s16x8*)(AsF + CA + aIdx + mt * 1024 + swz1); }   \
    _Pragma("unroll") for (int nt = 0; nt < 2; ++nt) {                       \
        b01_[nt][0] = *(const s16x8*)(BsF + CBB + bIdx + nt * 1024 + swz0);  \
        b01_[nt][1] = *(const s16x8*)(BsF + CBB + bIdx + nt * 1024 + swz1); }\
    if (ST1) { gl_lds16(gA2 + 64, AsF + NA + 2 * 4096 + w512);               \
               gl_lds16(gA3 + 64, AsF + NA + 3 * 4096 + w512); }             \
    BARRIER();                                                               \
    __builtin_amdgcn_s_setprio(1);                                           \
    _Pragma("unroll") for (int mt = 0; mt < 2; ++mt)                         \
      _Pragma("unroll") for (int nt = 0; nt < 2; ++nt)                       \
        _Pragma("unroll") for (int ks = 0; ks < 2; ++ks)                     \
          acc[mt][nt] = __builtin_amdgcn_mfma_f32_16x16x32_bf16(             \
              a_[mt][ks], b01_[nt][ks], acc[mt][nt], 0, 0, 0);               \
    __builtin_amdgcn_s_setprio(0);                                           \
    BARRIER();                                                               \
    /* ---- P2: read b23(4) ; stage A0,A1(t+2) -> CB ; MFMA a01 x b23 ---- */\
    _Pragma("unroll") for (int nt = 0; nt < 2; ++nt) {                       \
        b23_[nt][0] = *(const s16x8*)(BsF + CBB + bIdx + (nt+2)*1024 + swz0);\
        b23_[nt][1] = *(const s16x8*)(BsF + CBB + bIdx + (nt+2)*1024 + swz1);}\
    if (ST2) { gl_lds16(gA0 + 128, AsF + CA + 0 * 4096 + w512);              \
               gl_lds16(gA1 + 128, AsF + CA + 1 * 4096 + w512); }            \
    BARRIER();                                                               \
    __builtin_amdgcn_s_setprio(1);                                           \
    _Pragma("unroll") for (int mt = 0; mt < 2; ++mt)                         \
      _Pragma("unroll") for (int nt = 0; nt < 2; ++nt)                       \
        _Pragma("unroll") for (int ks = 0; ks < 2; ++ks)                     \
          acc[mt][nt + 2] = __builtin_amdgcn_mfma_f32_16x16x32_bf16(         \
              a_[mt][ks], b23_[nt][ks], acc[mt][nt + 2], 0, 0, 0);           \
    __builtin_amdgcn_s_setprio(0);                                           \
    BARRIER();                                                               \
    /* ---- P3: stage B0,B1(t+2) -> CB ; MFMA a23 x b01 ---- */              \
    if (ST2) { gl_lds16(gB0 + 128, BsF + CBB + 0 * 4096 + w512);             \
               gl_lds16(gB1 + 128, BsF + CBB + 1 * 4096 + w512); }           \
    BARRIER();                                                               \
    __builtin_amdgcn_s_setprio(1);                                           \
    _Pragma("unroll") for (int mt = 0; mt < 2; ++mt)                         \
      _Pragma("unroll") for (int nt = 0; nt < 2; ++nt)                       \
        _Pragma("unroll") for (int ks = 0; ks < 2; ++ks)                     \
          acc[2 + mt][nt] = __builtin_amdgcn_mfma_f32_16x16x32_bf16(         \
              a_[2 + mt][ks], b01_[nt][ks], acc[2 + mt][nt], 0, 0, 0);       \
    __builtin_amdgcn_s_setprio(0);                                           \
    BARRIER();                                                               \
    /* ---- P4: counted vmcnt ; MFMA a23 x b23 ---- */                       \
    if ((VM) == 4)      asm volatile("s_waitcnt vmcnt(4)" ::: "memory");     \
    else if ((VM) == 0) asm volatile("s_waitcnt vmcnt(0)" ::: "memory");     \
    BARRIER();                                                               \
    __builtin_amdgcn_s_setprio(1);                                           \
    _Pragma("unroll") for (int mt = 0; mt < 2; ++mt)                         \
      _Pragma("unroll") for (int nt = 0; nt < 2; ++nt)                       \
        _Pragma("unroll") for (int ks = 0; ks < 2; ++ks)                     \
          acc[2 + mt][nt + 2] = __builtin_amdgcn_mfma_f32_16x16x32_bf16(     \
              a_[2 + mt][ks], b23_[nt][ks], acc[2 + mt][nt + 2], 0, 0, 0);   \
    __builtin_amdgcn_s_setprio(0);                                           \
    BARRIER();                                                               \
} while (0)

    // ---- prologue: tile0 fully (6 loads) + tile1's A0,A1,B0,B1 (4) ----
    gl_lds16(gA0, AsF + 0 * 4096 + w512);
    gl_lds16(gA1, AsF + 1 * 4096 + w512);
    gl_lds16(gA2, AsF + 2 * 4096 + w512);
    gl_lds16(gA3, AsF + 3 * 4096 + w512);
    gl_lds16(gB0, BsF + 0 * 4096 + w512);
    gl_lds16(gB1, BsF + 1 * 4096 + w512);
    gl_lds16(gA0 + 64, AsF + 16384 + 0 * 4096 + w512);
    gl_lds16(gA1 + 64, AsF + 16384 + 1 * 4096 + w512);
    gl_lds16(gB0 + 64, BsF + 8192 + 0 * 4096 + w512);
    gl_lds16(gB1 + 64, BsF + 8192 + 1 * 4096 + w512);
    asm volatile("s_waitcnt vmcnt(4)" ::: "memory");   // drains exactly tile0
    BARRIER();

    // ---- main loop: t = 0..29, full staging, vmcnt(4) ----
    for (int tt = 0; tt < 15; ++tt) {
        KTILE(0, 1, 1, 4); ADV();
        KTILE(1, 1, 1, 4); ADV();
    }
    // ---- tail: t=30 (stage A2A3(31) only, drain all), t=31 (compute) ----
    KTILE(0, 1, 0, 0); ADV();
    KTILE(1, 0, 0, -1);

#undef KTILE
#undef ADV

    // ---- epilogue ----
    if (z == 2) {
#pragma unroll
        for (int mt = 0; mt < 4; ++mt) {
#pragma unroll
            for (int nt = 0; nt < 4; ++nt) {
                int col = n0 + wx * 64 + nt * 16 + l;     // h*128 + d
                float bv_ = bias[col];
                int row0 = m0 + wy * 64 + mt * 16 + quad * 4;  // = b*2048 + s0
                int bb = row0 >> 11, s0 = row0 & 2047;
                u16x4 o;
#pragma unroll
                for (int r = 0; r < 4; ++r) o[r] = f32_to_bf16(acc[mt][nt][r] + bv_);
                *(u16x4*)(VTo + ((size_t)(bb * 16) * 128 + col) * S_ + s0) = o;
            }
        }
    } else {
        // Q/K epilogue with fused RoPE.  d = wx*64 + nt*16 + l; roped dims
        // (d<64) live entirely in wx==0 waves; pair (2i,2i+1) = lanes (l,l^1).
        const bool do_rope = (wx == 0);
#pragma unroll
        for (int mt = 0; mt < 4; ++mt) {
#pragma unroll
            for (int nt = 0; nt < 4; ++nt) {
                int col = n0 + wx * 64 + nt * 16 + l;
                float bv_ = bias[col];
#pragma unroll
                for (int r = 0; r < 4; ++r) {
                    int row = m0 + wy * 64 + mt * 16 + quad * 4 + r;
                    float v = acc[mt][nt][r] + bv_;
                    if (do_rope) {
                        int s = row & 2047;
                        int i = (nt * 16 + l) >> 1;
                        float2 sc = tab[s * 32 + i];
                        float partner = __shfl_xor(v, 1, 64);
                        v = (l & 1) ? (v * sc.y + partner * sc.x)    // x1*c + x0*sn
                                    : (v * sc.y - partner * sc.x);   // x0*c - x1*sn
                    }
                    out[(size_t)row * HID_ + col] = f32_to_bf16(v);
                }
            }
        }
    }
}

// ---------------- flash attention: R4 design, unchanged --------------------
__global__ __launch_bounds__(512, 2) void flash_attn(const bhalf* __restrict__ Qb,
                                                     const bhalf* __restrict__ Kb,
                                                     const bhalf* __restrict__ VT,
                                                     const float* __restrict__ amask,
                                                     float* __restrict__ out) {
    __shared__ __align__(16) bhalf Kbuf[2][2048 * 8];   // 2 x 32KB
    __shared__ __align__(16) bhalf Vbuf[2][2048 * 8];   // 2 x 32KB
    const int tid = threadIdx.x, lane = tid & 63, w = tid >> 6;   // w 0..7
    const int quad = lane >> 4, l = lane & 15;
    const int pr = blockIdx.x, bh = blockIdx.y;
    const int b = bh >> 4, h = bh & 15;
    s16x8 ones;
#pragma unroll
    for (int j = 0; j < 8; ++j) ones[j] = (short)0x3F80;
    const int fpl = ((l >> 2) << 1) | (l & 1);   // fp(m=l) for P reads

    for (int pass = 0; pass < 2; ++pass) {
        const int jt = pass ? (15 - pr) : pr;        // q-tile index 0..15
        const int myrow = jt * 128 + w * 16;
        const int nch = jt + 1;                      // chunks needed (all waves)

        // Q A-fragments for my 16 rows: A[m=l][k=ks*32+quad*8+j]
        s16x8 qf[4];
        {
            const bhalf* Qrow = Qb + (size_t)(b * S_ + myrow + l) * HID_ + h * HD_;
#pragma unroll
            for (int ks = 0; ks < 4; ++ks)
                qf[ks] = *(const s16x8*)(Qrow + ks * 32 + quad * 8);
        }

        float m_run[4] = {-1e30f, -1e30f, -1e30f, -1e30f};
        f32x4 l_acc = {};
        f32x4 acc[8] = {};

        __syncthreads();   // prev pass's LDS reads complete before restaging

        // ---- prologue: stage chunk 0 into buffer 0 ----
#pragma unroll
        for (int j = 0; j < 4; ++j) {
            int slot0 = j * 512 + w * 64;            // wave-uniform
            int slot  = slot0 + lane;
            int row = slot >> 4, x = slot & 15;
            int g   = (x & 8) | ((x ^ row) & 7);
            gl_lds16(Kb + (size_t)(b * S_ + row) * HID_ + h * HD_ + g * 8,
                     &Kbuf[0][slot0 * 8]);
            gl_lds16(VT + ((size_t)bh * HD_ + row) * S_ + g * 8,
                     &Vbuf[0][slot0 * 8]);
        }

        for (int kc = 0; kc < nch; ++kc) {
            const int cur = kc & 1, nxt = cur ^ 1;
            const int key0 = kc * 128;
            __syncthreads();   // drains staging into cur; prior chunk's reads done

            const bool diag = (kc == jt);            // last chunk for ALL waves

            // mask row loads FIRST so their waitcnt doesn't drain staging below
            float am[8];
#pragma unroll
            for (int nt = 0; nt < 8; ++nt) am[nt] = amask[b * S_ + key0 + nt * 16 + l];
            // issue next chunk's staging (into nxt) — drained at next top barrier
            if (kc + 1 < nch) {
                const int key1 = key0 + 128;
#pragma unroll
                for (int j = 0; j < 4; ++j) {
                    int slot0 = j * 512 + w * 64;
                    int slot  = slot0 + lane;
                    int row = slot >> 4, x = slot & 15;
                    int g   = (x & 8) | ((x ^ row) & 7);
                    gl_lds16(Kb + (size_t)(b * S_ + key1 + row) * HID_ + h * HD_ + g * 8,
                             &Kbuf[nxt][slot0 * 8]);
                    gl_lds16(VT + ((size_t)bh * HD_ + row) * S_ + key1 + g * 8,
                             &Vbuf[nxt][slot0 * 8]);
                }
            }

            const bhalf* Kc = &Kbuf[cur][0];
            const bhalf* Vc = &Vbuf[cur][0];
            bhalf* Pw = &Kbuf[cur][0] + w * 2048;    // overlay, valid post-QK

            // ---- QK^T ----
            f32x4 s[8] = {};
#pragma unroll
            for (int nt = 0; nt < 8; ++nt) {
                int key = nt * 16 + l;
#pragma unroll
                for (int ks = 0; ks < 4; ++ks) {
                    int dg = ks * 4 + quad;
                    int x  = (dg & 8) | ((dg ^ key) & 7);
                    s16x8 kf = *(const s16x8*)(Kc + (key * 16 + x) * 8);
                    s[nt] = __builtin_amdgcn_mfma_f32_16x16x32_bf16(qf[ks], kf, s[nt], 0, 0, 0);
                }
            }
            // raw barrier: all QK reads of Kc retired (operands consumed pre-MFMA);
            // deliberately NO vmcnt drain so the nxt-buffer DMA stays in flight.
            __asm__ __volatile__("s_waitcnt lgkmcnt(0)\n\ts_barrier" ::: "memory");

            // ---- softmax (online) + P write (bf16, swizzled) ----
#pragma unroll
            for (int r = 0; r < 4; ++r) {
                const int qrow = myrow + quad * 4 + r;
                float p[8];
#pragma unroll
                for (int nt = 0; nt < 8; ++nt) {
                    float v = s[nt][r] * 0.08838834764831845f;   // 1/sqrt(128)
                    if (diag) { int key = key0 + nt * 16 + l; v = (key > qrow) ? MASKV : v; }
                    p[nt] = v + am[nt];
                }
                float mx = fmaxf(fmaxf(fmaxf(p[0], p[1]), fmaxf(p[2], p[3])),
                                 fmaxf(fmaxf(p[4], p[5]), fmaxf(p[6], p[7])));
#pragma unroll
                for (int msk = 1; msk < 16; msk <<= 1) mx = fmaxf(mx, __shfl_xor(mx, msk, 64));
                float m_new = fmaxf(m_run[r], mx);
                float alpha = __expf(m_run[r] - m_new);
                m_run[r] = m_new;
                const int m  = quad * 4 + r;
                const int fm = (quad << 1) | (r & 1);
#pragma unroll
                for (int nt = 0; nt < 8; ++nt) {
                    float e = __expf(p[nt] - m_new);
                    int key = nt * 16 + l;
                    Pw[(m * 16 + ((key >> 3) ^ fm)) * 8 + (key & 7)] = f32_to_bf16_trunc(e);
                }
                l_acc[r] *= alpha;
#pragma unroll
                for (int nt = 0; nt < 8; ++nt) acc[nt][r] *= alpha;
            }
            // ---- PV + ones row-sum ----
#pragma unroll
            for (int kstep = 0; kstep < 4; ++kstep) {
                int kg = kstep * 4 + quad;
                s16x8 pf = *(const s16x8*)(Pw + (l * 16 + (kg ^ fpl)) * 8);
                l_acc = __builtin_amdgcn_mfma_f32_16x16x32_bf16(pf, ones, l_acc, 0, 0, 0);
#pragma unroll
                for (int nt = 0; nt < 8; ++nt) {
                    int d = nt * 16 + l;
                    int x = (kg & 8) | ((kg ^ d) & 7);
                    s16x8 vf = *(const s16x8*)(Vc + (d * 16 + x) * 8);
                    acc[nt] = __builtin_amdgcn_mfma_f32_16x16x32_bf16(pf, vf, acc[nt], 0, 0, 0);
                }
            }
        }

        // ---- epilogue: O /= l, fp32 out (B,S,HID) ----
        float inv[4];
#pragma unroll
        for (int r = 0; r < 4; ++r) inv[r] = 1.f / l_acc[r];
#pragma unroll
        for (int nt = 0; nt < 8; ++nt) {
            int col = h * HD_ + nt * 16 + l;
#pragma unroll
            for (int r = 0; r < 4; ++r)
                out[(size_t)(b * S_ + myrow + quad * 4 + r) * HID_ + col] = acc[nt][r] * inv[r];
        }
    }
}

extern "C" void kernel_launch(void* const* d_in, const int* in_sizes, int n_in,
                              void* d_out, int out_size, void* d_ws, size_t ws_size,
                              hipStream_t stream) {
    const float* hs    = (const float*)d_in[0];
    const float* amask = (const float*)d_in[1];
    const float* Wq    = (const float*)d_in[2];
    const float* bq    = (const float*)d_in[3];
    const float* Wk    = (const float*)d_in[4];
    const float* bk    = (const float*)d_in[5];
    const float* Wv    = (const float*)d_in[6];
    const float* bv    = (const float*)d_in[7];
    float* out = (float*)d_out;

    bhalf* hsb = (bhalf*)d_ws;              // 8,388,608 elems
    bhalf* wqb = hsb + 8388608;             // 3 x 4,194,304 (contiguous)
    bhalf* wkb = wqb + 4194304;
    bhalf* wvb = wkb + 4194304;
    bhalf* Qb  = wvb + 4194304;             // Q,K: 2 x 8,388,608 (contiguous)
    bhalf* Kb  = Qb + 8388608;
    bhalf* VTb = Kb + 8388608;              // V^T written directly by qkv_gemm
    float2* tab = (float2*)(VTb + 8388608); // 65536 float2 = 512 KB

    cast_all<<<20736, 256, 0, stream>>>(hs, Wq, Wk, Wv, hsb, tab);
    qkv_gemm<<<dim3(16, 16, 3), 512, 0, stream>>>(hsb, wqb, bq, bk, bv, Qb, VTb, tab);
    flash_attn<<<dim3(8, 32), 512, 0, stream>>>(Qb, Kb, VTb, amask, out);
}

// Round 8
// 318.263 us; speedup vs baseline: 1.0679x; 1.0679x over previous
//
#include <hip/hip_runtime.h>

typedef unsigned short bhalf;          // bf16 bits
typedef __attribute__((ext_vector_type(4))) float    f32x4;
typedef __attribute__((ext_vector_type(8))) short    s16x8;
typedef __attribute__((ext_vector_type(4))) float    floatx4;
typedef __attribute__((ext_vector_type(4))) unsigned short u16x4;

#define B_  2
#define S_  2048
#define HID_ 2048
#define NH_ 16
#define HD_ 128
#define M_  (B_*S_)          // 4096
#define MASKV (-10000.0f)

__device__ __forceinline__ bhalf f32_to_bf16(float f) {
    union { float f; unsigned int u; } v; v.f = f;
    unsigned int r = v.u + 0x7FFFu + ((v.u >> 16) & 1u);   // RNE
    return (bhalf)(r >> 16);
}
__device__ __forceinline__ bhalf f32_to_bf16_trunc(float f) {
    union { float f; unsigned int u; } v; v.f = f;
    return (bhalf)(v.u >> 16);
}
__device__ __forceinline__ float bf16_to_f32(bhalf h) {
    union { unsigned int u; float f; } v; v.u = ((unsigned int)h) << 16;
    return v.f;
}

// async global->LDS, 16B per lane; LDS dest = wave-uniform base + lane*16
__device__ __forceinline__ void gl_lds16(const void* g, void* l) {
    __builtin_amdgcn_global_load_lds(
        (const __attribute__((address_space(1))) void*)g,
        (__attribute__((address_space(3))) void*)l, 16, 0, 0);
}

// raw barrier with memory clobber: stops compiler memory reordering across
// phases but (unlike sched_barrier(0)) leaves register scheduling free.
#define BARRIER() asm volatile("s_barrier" ::: "memory")

// ------- fused cast fp32 -> bf16 (hs+Wq+Wk+Wv) + RoPE table precompute -----
__global__ __launch_bounds__(256) void cast_all(const float* __restrict__ hs,
                                                const float* __restrict__ Wq,
                                                const float* __restrict__ Wk,
                                                const float* __restrict__ Wv,
                                                bhalf* __restrict__ dst,
                                                float2* __restrict__ tab) {
    if (blockIdx.x >= 20480) {                 // RoPE table: 65536 = 2048 x 32
        int idx = (blockIdx.x - 20480) * 256 + threadIdx.x;
        int i = idx & 31, s = idx >> 5;
        float inv = expf(-(float)i * 0.2878231366242557f);   // ln(10000)/32
        float ang = (float)s * inv;
        tab[idx] = make_float2(sinf(ang), cosf(ang));
        return;
    }
    int idx = blockIdx.x * 256 + threadIdx.x;           // 0 .. 5,242,879
    const float* src;
    if (idx < 2097152)      src = hs + (size_t)idx * 4;
    else if (idx < 3145728) src = Wq + (size_t)(idx - 2097152) * 4;
    else if (idx < 4194304) src = Wk + (size_t)(idx - 3145728) * 4;
    else                    src = Wv + (size_t)(idx - 4194304) * 4;
    floatx4 f = *(const floatx4*)src;
    u16x4 o;
    o.x = f32_to_bf16(f.x); o.y = f32_to_bf16(f.y);
    o.z = f32_to_bf16(f.z); o.w = f32_to_bf16(f.w);
    *(u16x4*)(dst + (size_t)idx * 4) = o;
}

// ---------------- fused QKV GEMM: 256x128 tile, 4-phase counted-vmcnt ------
// R7: exact revert to R5 (116.4 us, MfmaUtil 38).  R6's fused-rope epilogue
// cost +15 us in-kernel (64 shfl + 64 tab loads per lane) > the 8 us kernel
// + boundary it removed; reverted.
__global__ __launch_bounds__(512, 2) void qkv_gemm(const bhalf* __restrict__ A,
                                                   const bhalf* __restrict__ Wb,
                                                   const float* __restrict__ bq,
                                                   const float* __restrict__ bk,
                                                   const float* __restrict__ bv,
                                                   bhalf* __restrict__ Out,
                                                   bhalf* __restrict__ VTo) {
    __shared__ __align__(16) bhalf As[2][16384];   // 2 x 256 rows x 64 k
    __shared__ __align__(16) bhalf Bs[2][8192];    // 2 x 128 rows x 64 k
    const int tid  = threadIdx.x;
    const int lane = tid & 63, w = tid >> 6;
    const int quad = lane >> 4, l = lane & 15;
    const int wy = w >> 1, wx = w & 1;            // wave tile: 64 x 64
    const int m0 = blockIdx.x * 256, n0 = blockIdx.y * 128;
    const int z  = blockIdx.z;
    const bhalf* W    = Wb + (size_t)z * HID_ * HID_;
    const float* bias = (z == 0) ? bq : (z == 1) ? bk : bv;
    bhalf* out        = Out + (size_t)z * M_ * HID_;

    bhalf* AsF = &As[0][0];
    bhalf* BsF = &Bs[0][0];

    const int row_s = tid >> 3;                   // 0..63 within a stage unit
    const int kg_s  = (tid & 7) ^ (row_s & 7);    // inverse-swizzled source col-group
    const int w512  = w * 512;                    // wave-uniform LDS slot base

    // running global stage pointers (position = current K-tile t)
    const bhalf* gA0 = A + (size_t)(m0 +   0 + row_s) * HID_ + kg_s * 8;
    const bhalf* gA1 = A + (size_t)(m0 +  64 + row_s) * HID_ + kg_s * 8;
    const bhalf* gA2 = A + (size_t)(m0 + 128 + row_s) * HID_ + kg_s * 8;
    const bhalf* gA3 = A + (size_t)(m0 + 192 + row_s) * HID_ + kg_s * 8;
    const bhalf* gB0 = W + (size_t)(n0 +   0 + row_s) * HID_ + kg_s * 8;
    const bhalf* gB1 = W + (size_t)(n0 +  64 + row_s) * HID_ + kg_s * 8;

    // loop-invariant LDS fragment addressing: row&7 == l&7 for every frag row
    const int aIdx = (wy * 64 + l) * 64;           // element idx of A row base
    const int bIdx = (wx * 64 + l) * 64;           // element idx of B row base
    const int swz0 = ((0 + quad) ^ (l & 7)) * 8;   // ks=0 swizzled chunk
    const int swz1 = ((4 + quad) ^ (l & 7)) * 8;   // ks=1 swizzled chunk

    f32x4 acc[4][4] = {};

#define ADV() do { gA0 += 64; gA1 += 64; gA2 += 64; gA3 += 64;               \
                   gB0 += 64; gB1 += 64; } while (0)

#define KTILE(BUF, ST1, ST2, VM) do {                                        \
    const int CA = (BUF) * 16384, NA = ((BUF) ^ 1) * 16384;                  \
    const int CBB = (BUF) * 8192;                                            \
    s16x8 a_[4][2], b01_[2][2], b23_[2][2];                                  \
    /* ---- P1: read a(8) + b01(4) ; stage A2,A3(t+1) -> NB ---- */          \
    _Pragma("unroll") for (int mt = 0; mt < 4; ++mt) {                       \
        a_[mt][0] = *(const s16x8*)(AsF + CA + aIdx + mt * 1024 + swz0);     \
        a_[mt][1] = *(const s16x8*)(AsF + CA + aIdx + mt * 1024 + swz1); }   \
    _Pragma("unroll") for (int nt = 0; nt < 2; ++nt) {                       \
        b01_[nt][0] = *(const s16x8*)(BsF + CBB + bIdx + nt * 1024 + swz0);  \
        b01_[nt][1] = *(const s16x8*)(BsF + CBB + bIdx + nt * 1024 + swz1); }\
    if (ST1) { gl_lds16(gA2 + 64, AsF + NA + 2 * 4096 + w512);               \
               gl_lds16(gA3 + 64, AsF + NA + 3 * 4096 + w512); }             \
    BARRIER();                                                               \
    __builtin_amdgcn_s_setprio(1);                                           \
    _Pragma("unroll") for (int mt = 0; mt < 2; ++mt)                         \
      _Pragma("unroll") for (int nt = 0; nt < 2; ++nt)                       \
        _Pragma("unroll") for (int ks = 0; ks < 2; ++ks)                     \
          acc[mt][nt] = __builtin_amdgcn_mfma_f32_16x16x32_bf16(             \
              a_[mt][ks], b01_[nt][ks], acc[mt][nt], 0, 0, 0);               \
    __builtin_amdgcn_s_setprio(0);                                           \
    BARRIER();                                                               \
    /* ---- P2: read b23(4) ; stage A0,A1(t+2) -> CB ; MFMA a01 x b23 ---- */\
    _Pragma("unroll") for (int nt = 0; nt < 2; ++nt) {                       \
        b23_[nt][0] = *(const s16x8*)(BsF + CBB + bIdx + (nt+2)*1024 + swz0);\
        b23_[nt][1] = *(const s16x8*)(BsF + CBB + bIdx + (nt+2)*1024 + swz1);}\
    if (ST2) { gl_lds16(gA0 + 128, AsF + CA + 0 * 4096 + w512);              \
               gl_lds16(gA1 + 128, AsF + CA + 1 * 4096 + w512); }            \
    BARRIER();                                                               \
    __builtin_amdgcn_s_setprio(1);                                           \
    _Pragma("unroll") for (int mt = 0; mt < 2; ++mt)                         \
      _Pragma("unroll") for (int nt = 0; nt < 2; ++nt)                       \
        _Pragma("unroll") for (int ks = 0; ks < 2; ++ks)                     \
          acc[mt][nt + 2] = __builtin_amdgcn_mfma_f32_16x16x32_bf16(         \
              a_[mt][ks], b23_[nt][ks], acc[mt][nt + 2], 0, 0, 0);           \
    __builtin_amdgcn_s_setprio(0);                                           \
    BARRIER();                                                               \
    /* ---- P3: stage B0,B1(t+2) -> CB ; MFMA a23 x b01 ---- */              \
    if (ST2) { gl_lds16(gB0 + 128, BsF + CBB + 0 * 4096 + w512);             \
               gl_lds16(gB1 + 128, BsF + CBB + 1 * 4096 + w512); }           \
    BARRIER();                                                               \
    __builtin_amdgcn_s_setprio(1);                                           \
    _Pragma("unroll") for (int mt = 0; mt < 2; ++mt)                         \
      _Pragma("unroll") for (int nt = 0; nt < 2; ++nt)                       \
        _Pragma("unroll") for (int ks = 0; ks < 2; ++ks)                     \
          acc[2 + mt][nt] = __builtin_amdgcn_mfma_f32_16x16x32_bf16(         \
              a_[2 + mt][ks], b01_[nt][ks], acc[2 + mt][nt], 0, 0, 0);       \
    __builtin_amdgcn_s_setprio(0);                                           \
    BARRIER();                                                               \
    /* ---- P4: counted vmcnt ; MFMA a23 x b23 ---- */                       \
    if ((VM) == 4)      asm volatile("s_waitcnt vmcnt(4)" ::: "memory");     \
    else if ((VM) == 0) asm volatile("s_waitcnt vmcnt(0)" ::: "memory");     \
    BARRIER();                                                               \
    __builtin_amdgcn_s_setprio(1);                                           \
    _Pragma("unroll") for (int mt = 0; mt < 2; ++mt)                         \
      _Pragma("unroll") for (int nt = 0; nt < 2; ++nt)                       \
        _Pragma("unroll") for (int ks = 0; ks < 2; ++ks)                     \
          acc[2 + mt][nt + 2] = __builtin_amdgcn_mfma_f32_16x16x32_bf16(     \
              a_[2 + mt][ks], b23_[nt][ks], acc[2 + mt][nt + 2], 0, 0, 0);   \
    __builtin_amdgcn_s_setprio(0);                                           \
    BARRIER();                                                               \
} while (0)

    // ---- prologue: tile0 fully (6 loads) + tile1's A0,A1,B0,B1 (4) ----
    gl_lds16(gA0, AsF + 0 * 4096 + w512);
    gl_lds16(gA1, AsF + 1 * 4096 + w512);
    gl_lds16(gA2, AsF + 2 * 4096 + w512);
    gl_lds16(gA3, AsF + 3 * 4096 + w512);
    gl_lds16(gB0, BsF + 0 * 4096 + w512);
    gl_lds16(gB1, BsF + 1 * 4096 + w512);
    gl_lds16(gA0 + 64, AsF + 16384 + 0 * 4096 + w512);
    gl_lds16(gA1 + 64, AsF + 16384 + 1 * 4096 + w512);
    gl_lds16(gB0 + 64, BsF + 8192 + 0 * 4096 + w512);
    gl_lds16(gB1 + 64, BsF + 8192 + 1 * 4096 + w512);
    asm volatile("s_waitcnt vmcnt(4)" ::: "memory");   // drains exactly tile0
    BARRIER();

    // ---- main loop: t = 0..29, full staging, vmcnt(4) ----
    for (int tt = 0; tt < 15; ++tt) {
        KTILE(0, 1, 1, 4); ADV();
        KTILE(1, 1, 1, 4); ADV();
    }
    // ---- tail: t=30 (stage A2A3(31) only, drain all), t=31 (compute) ----
    KTILE(0, 1, 0, 0); ADV();
    KTILE(1, 0, 0, -1);

#undef KTILE
#undef ADV

    // ---- epilogue ----
    if (z == 2) {
#pragma unroll
        for (int mt = 0; mt < 4; ++mt) {
#pragma unroll
            for (int nt = 0; nt < 4; ++nt) {
                int col = n0 + wx * 64 + nt * 16 + l;     // h*128 + d
                float bv_ = bias[col];
                int row0 = m0 + wy * 64 + mt * 16 + quad * 4;  // = b*2048 + s0
                int bb = row0 >> 11, s0 = row0 & 2047;
                u16x4 o;
#pragma unroll
                for (int r = 0; r < 4; ++r) o[r] = f32_to_bf16(acc[mt][nt][r] + bv_);
                *(u16x4*)(VTo + ((size_t)(bb * 16) * 128 + col) * S_ + s0) = o;
            }
        }
    } else {
#pragma unroll
        for (int mt = 0; mt < 4; ++mt) {
#pragma unroll
            for (int nt = 0; nt < 4; ++nt) {
                int col = n0 + wx * 64 + nt * 16 + l;
                float bv_ = bias[col];
#pragma unroll
                for (int r = 0; r < 4; ++r) {
                    int row = m0 + wy * 64 + mt * 16 + quad * 4 + r;
                    out[(size_t)row * HID_ + col] = f32_to_bf16(acc[mt][nt][r] + bv_);
                }
            }
        }
    }
}

// ---------------- RoPE apply (table comes from cast_all) -------------------
__global__ __launch_bounds__(256) void rope_apply(bhalf* __restrict__ Qb,
                                                  bhalf* __restrict__ Kb,
                                                  const float2* __restrict__ tab) {
    int flat = blockIdx.x * 256 + threadIdx.x;   // 2,097,152
    int i = flat & 31;
    int h = (flat >> 5) & 15;
    int s = (flat >> 9) & 2047;
    int b = flat >> 20;
    size_t base = ((size_t)(b * S_ + s)) * HID_ + h * HD_ + 2 * i;
    float2 sc = tab[s * 32 + i];
    float c = sc.y, sn = sc.x;
    {
        unsigned int q = *(const unsigned int*)(Qb + base);
        float x0 = bf16_to_f32((bhalf)(q & 0xffff));
        float x1 = bf16_to_f32((bhalf)(q >> 16));
        unsigned int o = (unsigned int)f32_to_bf16(x0 * c - x1 * sn)
                       | ((unsigned int)f32_to_bf16(x1 * c + x0 * sn) << 16);
        *(unsigned int*)(Qb + base) = o;
    }
    {
        unsigned int k = *(const unsigned int*)(Kb + base);
        float x0 = bf16_to_f32((bhalf)(k & 0xffff));
        float x1 = bf16_to_f32((bhalf)(k >> 16));
        unsigned int o = (unsigned int)f32_to_bf16(x0 * c - x1 * sn)
                       | ((unsigned int)f32_to_bf16(x1 * c + x0 * sn) << 16);
        *(unsigned int*)(Kb + base) = o;
    }
}

// ---------------- flash attention: R4 body, XCD-local K/V sharing ----------
// R7: grid swapped to (bh=32, pr=8).  XCD = flat&7 = bh&7, so all 8 pr-blocks
// of a (b,h) — which read the SAME K/V stream in the SAME ascending chunk
// order from kc=0 — land on ONE XCD and share its L2 (was: spread over all 8
// XCDs, 8x duplicate L3/HBM streams, 64MB working set per XCD).  Per-XCD
// working set drops to 4 bh x 2MB = 8MB with 8-way temporal chunk sharing.
__global__ __launch_bounds__(512, 2) void flash_attn(const bhalf* __restrict__ Qb,
                                                     const bhalf* __restrict__ Kb,
                                                     const bhalf* __restrict__ VT,
                                                     const float* __restrict__ amask,
                                                     float* __restrict__ out) {
    __shared__ __align__(16) bhalf Kbuf[2][2048 * 8];   // 2 x 32KB
    __shared__ __align__(16) bhalf Vbuf[2][2048 * 8];   // 2 x 32KB
    const int tid = threadIdx.x, lane = tid & 63, w = tid >> 6;   // w 0..7
    const int quad = lane >> 4, l = lane & 15;
    const int bh = blockIdx.x, pr = blockIdx.y;         // XCD = bh & 7
    const int b = bh >> 4, h = bh & 15;
    s16x8 ones;
#pragma unroll
    for (int j = 0; j < 8; ++j) ones[j] = (short)0x3F80;
    const int fpl = ((l >> 2) << 1) | (l & 1);   // fp(m=l) for P reads

    for (int pass = 0; pass < 2; ++pass) {
        const int jt = pass ? (15 - pr) : pr;        // q-tile index 0..15
        const int myrow = jt * 128 + w * 16;
        const int nch = jt + 1;                      // chunks needed (all waves)

        // Q A-fragments for my 16 rows: A[m=l][k=ks*32+quad*8+j]
        s16x8 qf[4];
        {
            const bhalf* Qrow = Qb + (size_t)(b * S_ + myrow + l) * HID_ + h * HD_;
#pragma unroll
            for (int ks = 0; ks < 4; ++ks)
                qf[ks] = *(const s16x8*)(Qrow + ks * 32 + quad * 8);
        }

        float m_run[4] = {-1e30f, -1e30f, -1e30f, -1e30f};
        f32x4 l_acc = {};
        f32x4 acc[8] = {};

        __syncthreads();   // prev pass's LDS reads complete before restaging

        // ---- prologue: stage chunk 0 into buffer 0 ----
#pragma unroll
        for (int j = 0; j < 4; ++j) {
            int slot0 = j * 512 + w * 64;            // wave-uniform
            int slot  = slot0 + lane;
            int row = slot >> 4, x = slot & 15;
            int g   = (x & 8) | ((x ^ row) & 7);
            gl_lds16(Kb + (size_t)(b * S_ + row) * HID_ + h * HD_ + g * 8,
                     &Kbuf[0][slot0 * 8]);
            gl_lds16(VT + ((size_t)bh * HD_ + row) * S_ + g * 8,
                     &Vbuf[0][slot0 * 8]);
        }

        for (int kc = 0; kc < nch; ++kc) {
            const int cur = kc & 1, nxt = cur ^ 1;
            const int key0 = kc * 128;
            __syncthreads();   // drains staging into cur; prior chunk's reads done

            const bool diag = (kc == jt);            // last chunk for ALL waves

            // mask row loads FIRST so their waitcnt doesn't drain staging below
            float am[8];
#pragma unroll
            for (int nt = 0; nt < 8; ++nt) am[nt] = amask[b * S_ + key0 + nt * 16 + l];
            // issue next chunk's staging (into nxt) — drained at next top barrier
            if (kc + 1 < nch) {
                const int key1 = key0 + 128;
#pragma unroll
                for (int j = 0; j < 4; ++j) {
                    int slot0 = j * 512 + w * 64;
                    int slot  = slot0 + lane;
                    int row = slot >> 4, x = slot & 15;
                    int g   = (x & 8) | ((x ^ row) & 7);
                    gl_lds16(Kb + (size_t)(b * S_ + key1 + row) * HID_ + h * HD_ + g * 8,
                             &Kbuf[nxt][slot0 * 8]);
                    gl_lds16(VT + ((size_t)bh * HD_ + row) * S_ + key1 + g * 8,
                             &Vbuf[nxt][slot0 * 8]);
                }
            }

            const bhalf* Kc = &Kbuf[cur][0];
            const bhalf* Vc = &Vbuf[cur][0];
            bhalf* Pw = &Kbuf[cur][0] + w * 2048;    // overlay, valid post-QK

            // ---- QK^T ----
            f32x4 s[8] = {};
#pragma unroll
            for (int nt = 0; nt < 8; ++nt) {
                int key = nt * 16 + l;
#pragma unroll
                for (int ks = 0; ks < 4; ++ks) {
                    int dg = ks * 4 + quad;
                    int x  = (dg & 8) | ((dg ^ key) & 7);
                    s16x8 kf = *(const s16x8*)(Kc + (key * 16 + x) * 8);
                    s[nt] = __builtin_amdgcn_mfma_f32_16x16x32_bf16(qf[ks], kf, s[nt], 0, 0, 0);
                }
            }
            // raw barrier: all QK reads of Kc retired (operands consumed pre-MFMA);
            // deliberately NO vmcnt drain so the nxt-buffer DMA stays in flight.
            __asm__ __volatile__("s_waitcnt lgkmcnt(0)\n\ts_barrier" ::: "memory");

            // ---- softmax (online) + P write (bf16, swizzled) ----
#pragma unroll
            for (int r = 0; r < 4; ++r) {
                const int qrow = myrow + quad * 4 + r;
                float p[8];
#pragma unroll
                for (int nt = 0; nt < 8; ++nt) {
                    float v = s[nt][r] * 0.08838834764831845f;   // 1/sqrt(128)
                    if (diag) { int key = key0 + nt * 16 + l; v = (key > qrow) ? MASKV : v; }
                    p[nt] = v + am[nt];
                }
                float mx = fmaxf(fmaxf(fmaxf(p[0], p[1]), fmaxf(p[2], p[3])),
                                 fmaxf(fmaxf(p[4], p[5]), fmaxf(p[6], p[7])));
#pragma unroll
                for (int msk = 1; msk < 16; msk <<= 1) mx = fmaxf(mx, __shfl_xor(mx, msk, 64));
                float m_new = fmaxf(m_run[r], mx);
                float alpha = __expf(m_run[r] - m_new);
                m_run[r] = m_new;
                const int m  = quad * 4 + r;
                const int fm = (quad << 1) | (r & 1);
#pragma unroll
                for (int nt = 0; nt < 8; ++nt) {
                    float e = __expf(p[nt] - m_new);
                    int key = nt * 16 + l;
                    Pw[(m * 16 + ((key >> 3) ^ fm)) * 8 + (key & 7)] = f32_to_bf16_trunc(e);
                }
                l_acc[r] *= alpha;
#pragma unroll
                for (int nt = 0; nt < 8; ++nt) acc[nt][r] *= alpha;
            }
            // ---- PV + ones row-sum ----
#pragma unroll
            for (int kstep = 0; kstep < 4; ++kstep) {
                int kg = kstep * 4 + quad;
                s16x8 pf = *(const s16x8*)(Pw + (l * 16 + (kg ^ fpl)) * 8);
                l_acc = __builtin_amdgcn_mfma_f32_16x16x32_bf16(pf, ones, l_acc, 0, 0, 0);
#pragma unroll
                for (int nt = 0; nt < 8; ++nt) {
                    int d = nt * 16 + l;
                    int x = (kg & 8) | ((kg ^ d) & 7);
                    s16x8 vf = *(const s16x8*)(Vc + (d * 16 + x) * 8);
                    acc[nt] = __builtin_amdgcn_mfma_f32_16x16x32_bf16(pf, vf, acc[nt], 0, 0, 0);
                }
            }
        }

        // ---- epilogue: O /= l, fp32 out (B,S,HID) ----
        float inv[4];
#pragma unroll
        for (int r = 0; r < 4; ++r) inv[r] = 1.f / l_acc[r];
#pragma unroll
        for (int nt = 0; nt < 8; ++nt) {
            int col = h * HD_ + nt * 16 + l;
#pragma unroll
            for (int r = 0; r < 4; ++r)
                out[(size_t)(b * S_ + myrow + quad * 4 + r) * HID_ + col] = acc[nt][r] * inv[r];
        }
    }
}

extern "C" void kernel_launch(void* const* d_in, const int* in_sizes, int n_in,
                              void* d_out, int out_size, void* d_ws, size_t ws_size,
                              hipStream_t stream) {
    const float* hs    = (const float*)d_in[0];
    const float* amask = (const float*)d_in[1];
    const float* Wq    = (const float*)d_in[2];
    const float* bq    = (const float*)d_in[3];
    const float* Wk    = (const float*)d_in[4];
    const float* bk    = (const float*)d_in[5];
    const float* Wv    = (const float*)d_in[6];
    const float* bv    = (const float*)d_in[7];
    float* out = (float*)d_out;

    bhalf* hsb = (bhalf*)d_ws;              // 8,388,608 elems
    bhalf* wqb = hsb + 8388608;             // 3 x 4,194,304 (contiguous)
    bhalf* wkb = wqb + 4194304;
    bhalf* wvb = wkb + 4194304;
    bhalf* Qb  = wvb + 4194304;             // Q,K: 2 x 8,388,608 (contiguous)
    bhalf* Kb  = Qb + 8388608;
    bhalf* VTb = Kb + 8388608;              // V^T written directly by qkv_gemm
    float2* tab = (float2*)(VTb + 8388608); // 65536 float2 = 512 KB

    cast_all<<<20736, 256, 0, stream>>>(hs, Wq, Wk, Wv, hsb, tab);
    qkv_gemm<<<dim3(16, 16, 3), 512, 0, stream>>>(hsb, wqb, bq, bk, bv, Qb, VTb);
    rope_apply<<<8192, 256, 0, stream>>>(Qb, Kb, tab);
    flash_attn<<<dim3(32, 8), 512, 0, stream>>>(Qb, Kb, VTb, amask, out);
}